// Round 1
// baseline (5883.357 us; speedup 1.0000x reference)
//
#include <hip/hip_runtime.h>

// Problem constants
#define BB 4
#define SS 2048
#define DD 1024
#define HH 16
#define HDIM 64
#define PFF 4096
#define MROWS (BB * SS)          // 8192
static_assert(MROWS == 8192, "");

// ---------------------------------------------------------------------------
// fp32 tiled GEMM: C[M,N] = A[M,K] @ W[K,N] + bias[N]  (optional ReLU)
// 64x64 tile, BK=16, 256 threads, 4x4 acc per thread.
// ---------------------------------------------------------------------------
template <int RELU>
__global__ __launch_bounds__(256) void gemm_f32(
    const float* __restrict__ A, const float* __restrict__ W,
    const float* __restrict__ bias, float* __restrict__ C,
    int M, int N, int K) {
  __shared__ float As[64][17];   // +1 pad: a-reads conflict-free
  __shared__ float Bs[16][64];

  const int t = threadIdx.x;
  const int tx = t & 15;         // output col group
  const int ty = t >> 4;         // output row group
  const int row0 = blockIdx.y * 64;
  const int col0 = blockIdx.x * 64;

  // loader indices
  const int la_r = t >> 2;            // 0..63
  const int la_c = (t & 3) << 2;      // 0,4,8,12
  const int lb_r = t >> 4;            // 0..15
  const int lb_c = (t & 15) << 2;     // 0..60

  float acc[4][4] = {};

  for (int k0 = 0; k0 < K; k0 += 16) {
    float4 av = *(const float4*)&A[(size_t)(row0 + la_r) * K + (k0 + la_c)];
    float4 bv = *(const float4*)&W[(size_t)(k0 + lb_r) * N + (col0 + lb_c)];
    __syncthreads();  // previous iteration's LDS reads done
    As[la_r][la_c + 0] = av.x;
    As[la_r][la_c + 1] = av.y;
    As[la_r][la_c + 2] = av.z;
    As[la_r][la_c + 3] = av.w;
    *(float4*)&Bs[lb_r][lb_c] = bv;
    __syncthreads();
#pragma unroll
    for (int kk = 0; kk < 16; ++kk) {
      float a0 = As[4 * ty + 0][kk];
      float a1 = As[4 * ty + 1][kk];
      float a2 = As[4 * ty + 2][kk];
      float a3 = As[4 * ty + 3][kk];
      float4 b4 = *(const float4*)&Bs[kk][tx * 4];
      acc[0][0] += a0 * b4.x; acc[0][1] += a0 * b4.y; acc[0][2] += a0 * b4.z; acc[0][3] += a0 * b4.w;
      acc[1][0] += a1 * b4.x; acc[1][1] += a1 * b4.y; acc[1][2] += a1 * b4.z; acc[1][3] += a1 * b4.w;
      acc[2][0] += a2 * b4.x; acc[2][1] += a2 * b4.y; acc[2][2] += a2 * b4.z; acc[2][3] += a2 * b4.w;
      acc[3][0] += a3 * b4.x; acc[3][1] += a3 * b4.y; acc[3][2] += a3 * b4.z; acc[3][3] += a3 * b4.w;
    }
  }

  float4 b4 = *(const float4*)&bias[col0 + tx * 4];
#pragma unroll
  for (int i = 0; i < 4; ++i) {
    float4 r;
    r.x = acc[i][0] + b4.x;
    r.y = acc[i][1] + b4.y;
    r.z = acc[i][2] + b4.z;
    r.w = acc[i][3] + b4.w;
    if (RELU) {
      r.x = fmaxf(r.x, 0.f); r.y = fmaxf(r.y, 0.f);
      r.z = fmaxf(r.z, 0.f); r.w = fmaxf(r.w, 0.f);
    }
    *(float4*)&C[(size_t)(row0 + 4 * ty + i) * N + (col0 + tx * 4)] = r;
  }
}

// ---------------------------------------------------------------------------
// Flash-style fp32 attention.
// Q,K,V stored as [B, S, H, HD] (= GEMM output [B*S, D]); O same layout.
// Grid: (S/32, B*H). Block: 256 threads.
// Thread t: qi = t>>3 (0..31), lane-in-group = t&7.
//   scores: kj = (t&7) + 8*jj, jj=0..7
//   output: dj = (t&7)*8 + j, j=0..7
// Online softmax state (m,l) kept redundantly in each 8-lane group's regs.
// ---------------------------------------------------------------------------
__global__ __launch_bounds__(256) void attn_f32(
    const float* __restrict__ Qg, const float* __restrict__ Kg,
    const float* __restrict__ Vg, float* __restrict__ Og) {
  const int bh = blockIdx.y;
  const int b = bh >> 4;
  const int h = bh & 15;
  const int q0 = blockIdx.x * 32;
  const int t = threadIdx.x;
  const int qi = t >> 3;
  const int lg = t & 7;

  const size_t base = ((size_t)b * SS) * DD + (size_t)h * HDIM;  // + s*DD + d

  __shared__ float Qs[32][HDIM];        // 8 KB (reads are broadcast-ish, once)
  __shared__ float Ks[64][HDIM + 2];    // stride 66: conflict-free score reads
  __shared__ float Vs[64][HDIM];        // 16 KB
  __shared__ float Ps[32][66];          // stride 66: conflict-free PV reads

  // ---- stage Q tile (coalesced), move own row to registers ----
  for (int j = 0; j < 2; ++j) {
    int f4 = t + 256 * j;               // 512 float4s = 32*64 floats
    int r = f4 >> 4, c4 = f4 & 15;
    *(float4*)&Qs[r][c4 * 4] =
        *(const float4*)&Qg[base + (size_t)(q0 + r) * DD + c4 * 4];
  }
  __syncthreads();
  float2 qr[32];
#pragma unroll
  for (int d2 = 0; d2 < 32; ++d2) qr[d2] = *(const float2*)&Qs[qi][2 * d2];

  float o[8] = {};
  float m_run = -1e30f, l_run = 0.f;
  const float scale = 0.125f;  // 1/sqrt(64)

  for (int kt = 0; kt < SS / 64; ++kt) {
    const int s0 = kt * 64;
    __syncthreads();  // previous tile's LDS reads done
    // ---- stage K,V tiles (coalesced) ----
    for (int j = 0; j < 4; ++j) {
      int f4 = t + 256 * j;             // 1024 float4s = 64*64 floats
      int r = f4 >> 4, c4 = f4 & 15;
      float4 kv = *(const float4*)&Kg[base + (size_t)(s0 + r) * DD + c4 * 4];
      float4 vv = *(const float4*)&Vg[base + (size_t)(s0 + r) * DD + c4 * 4];
      *(float2*)&Ks[r][c4 * 4] = make_float2(kv.x, kv.y);
      *(float2*)&Ks[r][c4 * 4 + 2] = make_float2(kv.z, kv.w);
      *(float4*)&Vs[r][c4 * 4] = vv;
    }
    __syncthreads();

    // ---- scores for my 8 keys ----
    float s[8];
#pragma unroll
    for (int jj = 0; jj < 8; ++jj) {
      const int kj = lg + 8 * jj;
      float acc = 0.f;
#pragma unroll
      for (int d2 = 0; d2 < 32; ++d2) {
        float2 k2 = *(const float2*)&Ks[kj][2 * d2];
        acc += qr[d2].x * k2.x + qr[d2].y * k2.y;
      }
      s[jj] = acc * scale;
    }

    // ---- online softmax (within 8-lane group) ----
    float tm = s[0];
#pragma unroll
    for (int jj = 1; jj < 8; ++jj) tm = fmaxf(tm, s[jj]);
    tm = fmaxf(tm, __shfl_xor(tm, 1));
    tm = fmaxf(tm, __shfl_xor(tm, 2));
    tm = fmaxf(tm, __shfl_xor(tm, 4));
    const float m_new = fmaxf(m_run, tm);
    const float rf = __expf(m_run - m_new);
    float psum = 0.f;
#pragma unroll
    for (int jj = 0; jj < 8; ++jj) {
      float p = __expf(s[jj] - m_new);
      Ps[qi][lg + 8 * jj] = p;
      psum += p;
    }
    psum += __shfl_xor(psum, 1);
    psum += __shfl_xor(psum, 2);
    psum += __shfl_xor(psum, 4);
    l_run = l_run * rf + psum;
    m_run = m_new;
    __syncthreads();  // Ps visible

    // ---- O = O*rf + P @ V ----
#pragma unroll
    for (int j = 0; j < 8; ++j) o[j] *= rf;
    for (int kk = 0; kk < 64; ++kk) {
      float p = Ps[qi][kk];
      float4 va = *(const float4*)&Vs[kk][lg * 8];
      float4 vb = *(const float4*)&Vs[kk][lg * 8 + 4];
      o[0] += p * va.x; o[1] += p * va.y; o[2] += p * va.z; o[3] += p * va.w;
      o[4] += p * vb.x; o[5] += p * vb.y; o[6] += p * vb.z; o[7] += p * vb.w;
    }
  }

  const float inv = 1.f / l_run;
  float4 ra, rb;
  ra.x = o[0] * inv; ra.y = o[1] * inv; ra.z = o[2] * inv; ra.w = o[3] * inv;
  rb.x = o[4] * inv; rb.y = o[5] * inv; rb.z = o[6] * inv; rb.w = o[7] * inv;
  float* op = &Og[base + (size_t)(q0 + qi) * DD + lg * 8];
  *(float4*)op = ra;
  *(float4*)(op + 4) = rb;
}

// ---------------------------------------------------------------------------
// Residual + LayerNorm: Y[row] = LN(X[row] + R[row]) * g + b
// Grid: 8192 blocks (one per row), 256 threads (4 floats each).
// ---------------------------------------------------------------------------
__global__ __launch_bounds__(256) void ln_res(
    const float* __restrict__ X, const float* __restrict__ R,
    const float* __restrict__ g, const float* __restrict__ b,
    float* __restrict__ Y) {
  const int row = blockIdx.x;
  const int t = threadIdx.x;
  const size_t off = (size_t)row * DD + t * 4;

  float4 x4 = *(const float4*)&X[off];
  float4 r4 = *(const float4*)&R[off];
  float v0 = x4.x + r4.x, v1 = x4.y + r4.y, v2 = x4.z + r4.z, v3 = x4.w + r4.w;

  float s1 = v0 + v1 + v2 + v3;
  float s2 = v0 * v0 + v1 * v1 + v2 * v2 + v3 * v3;
#pragma unroll
  for (int o = 1; o < 64; o <<= 1) {
    s1 += __shfl_xor(s1, o);
    s2 += __shfl_xor(s2, o);
  }
  __shared__ float red1[4], red2[4];
  if ((t & 63) == 0) {
    red1[t >> 6] = s1;
    red2[t >> 6] = s2;
  }
  __syncthreads();
  s1 = red1[0] + red1[1] + red1[2] + red1[3];
  s2 = red2[0] + red2[1] + red2[2] + red2[3];

  const float mu = s1 * (1.f / DD);
  const float var = s2 * (1.f / DD) - mu * mu;
  const float rs = rsqrtf(var + 1e-5f);

  float4 g4 = *(const float4*)&g[t * 4];
  float4 b4 = *(const float4*)&b[t * 4];
  float4 y;
  y.x = (v0 - mu) * rs * g4.x + b4.x;
  y.y = (v1 - mu) * rs * g4.y + b4.y;
  y.z = (v2 - mu) * rs * g4.z + b4.z;
  y.w = (v3 - mu) * rs * g4.w + b4.w;
  *(float4*)&Y[off] = y;
}

// ---------------------------------------------------------------------------
extern "C" void kernel_launch(void* const* d_in, const int* in_sizes, int n_in,
                              void* d_out, int out_size, void* d_ws,
                              size_t ws_size, hipStream_t stream) {
  const float* src = (const float*)d_in[0];
  const float* Wq  = (const float*)d_in[1];
  const float* bq  = (const float*)d_in[2];
  const float* Wk  = (const float*)d_in[3];
  const float* bk  = (const float*)d_in[4];
  const float* Wv  = (const float*)d_in[5];
  const float* bv  = (const float*)d_in[6];
  const float* Wo  = (const float*)d_in[7];
  const float* bo  = (const float*)d_in[8];
  const float* g1  = (const float*)d_in[9];
  const float* b1  = (const float*)d_in[10];
  const float* W1  = (const float*)d_in[11];
  const float* bf1 = (const float*)d_in[12];
  const float* W2  = (const float*)d_in[13];
  const float* bf2 = (const float*)d_in[14];
  const float* g2  = (const float*)d_in[15];
  const float* b2  = (const float*)d_in[16];

  float* ws = (float*)d_ws;
  const size_t MS = (size_t)MROWS * DD;  // 8.39M floats
  // buffer plan (peak 6*MS floats = 201 MB):
  float* qb  = ws + 0 * MS;
  float* kb  = ws + 1 * MS;
  float* vb  = ws + 2 * MS;
  float* xb  = ws + 3 * MS;   // attention output
  float* pb  = qb;            // proj output (q dead after attention)
  float* s1b = ws + 4 * MS;   // LN1 output
  float* f1b = ws + 0 * MS;   // FFN hidden (q,k,v,x dead) — 4*MS floats
  float* f2b = ws + 5 * MS;   // FFN output

  dim3 blk(256);

  // QKV projections
  gemm_f32<0><<<dim3(DD / 64, MROWS / 64), blk, 0, stream>>>(src, Wq, bq, qb, MROWS, DD, DD);
  gemm_f32<0><<<dim3(DD / 64, MROWS / 64), blk, 0, stream>>>(src, Wk, bk, kb, MROWS, DD, DD);
  gemm_f32<0><<<dim3(DD / 64, MROWS / 64), blk, 0, stream>>>(src, Wv, bv, vb, MROWS, DD, DD);

  // attention
  attn_f32<<<dim3(SS / 32, BB * HH), blk, 0, stream>>>(qb, kb, vb, xb);

  // output projection
  gemm_f32<0><<<dim3(DD / 64, MROWS / 64), blk, 0, stream>>>(xb, Wo, bo, pb, MROWS, DD, DD);

  // residual + LN1
  ln_res<<<dim3(MROWS), blk, 0, stream>>>(src, pb, g1, b1, s1b);

  // FFN
  gemm_f32<1><<<dim3(PFF / 64, MROWS / 64), blk, 0, stream>>>(s1b, W1, bf1, f1b, MROWS, PFF, DD);
  gemm_f32<0><<<dim3(DD / 64, MROWS / 64), blk, 0, stream>>>(f1b, W2, bf2, f2b, MROWS, DD, PFF);

  // residual + LN2 -> output
  ln_res<<<dim3(MROWS), blk, 0, stream>>>(s1b, f2b, g2, b2, (float*)d_out);
}

// Round 2
// 531.325 us; speedup vs baseline: 11.0730x; 11.0730x over previous
//
#include <hip/hip_runtime.h>

#define BB 4
#define SS 2048
#define DD 1024
#define HH 16
#define PFF 4096
#define MR 8192

typedef unsigned short u16;
typedef __attribute__((ext_vector_type(8))) short s16x8;   // MFMA A/B frag (8 bf16)
typedef __attribute__((ext_vector_type(4))) float f32x4v;  // MFMA C/D frag
typedef __attribute__((ext_vector_type(4))) unsigned short u16x4;
typedef __attribute__((ext_vector_type(8))) unsigned short u16x8;

__device__ inline u16 f2bf(float f) {
  union { float f; unsigned u; } v; v.f = f;
  unsigned r = v.u + 0x7FFFu + ((v.u >> 16) & 1u);
  return (u16)(r >> 16);
}

__device__ inline void gload16(const void* g, void* l) {
  __builtin_amdgcn_global_load_lds(
      (const __attribute__((address_space(1))) void*)g,
      (__attribute__((address_space(3))) void*)l, 16, 0, 0);
}

__device__ inline f32x4v MFMA(s16x8 a, s16x8 b, f32x4v c) {
  return __builtin_amdgcn_mfma_f32_16x16x32_bf16(a, b, c, 0, 0, 0);
}

// read a b128 fragment from a 64-col bf16 LDS tile with (row&7)<<4 byte-XOR swizzle
__device__ inline s16x8 ldfrag(const u16* base, int row, int colByte) {
  return *(const s16x8*)((const char*)base + row * 128 + (colByte ^ ((row & 7) << 4)));
}

// ---------------------------------------------------------------------------
// bf16 MFMA GEMM, m97 structure: C[M,N] = A[M,K] @ Bt[N,K]^T + bias
// 128x128 tile, BK=32, 256 thr (4 waves 2x2), 4x4 frags of 16x16x32 per wave.
// ---------------------------------------------------------------------------
template <int RELU, int OUTBF>
__global__ __launch_bounds__(256) void gemm_bf16(
    const u16* __restrict__ A, const u16* __restrict__ Bt,
    const float* __restrict__ bias, float* __restrict__ Cf,
    u16* __restrict__ Cb, int M, int N, int K) {
  __shared__ __align__(128) u16 As[128 * 32];
  __shared__ __align__(128) u16 Bs[128 * 32];
  const int t = threadIdx.x;
  const int lane = t & 63, w = t >> 6;
  const int wr = w >> 1, wc = w & 1;
  const int g = lane >> 4, q = lane & 15;
  const int row0 = blockIdx.y * 128, col0 = blockIdx.x * 128;

  f32x4v acc[4][4];
#pragma unroll
  for (int m = 0; m < 4; ++m)
#pragma unroll
    for (int n = 0; n < 4; ++n) acc[m][n] = (f32x4v){0.f, 0.f, 0.f, 0.f};

  const int c0 = t, c1 = 256 + t;
  const int ar0 = c0 >> 2, ac0 = (c0 & 3) * 8;
  const int ar1 = c1 >> 2, ac1 = (c1 & 3) * 8;
  const u16* Ar0 = A + (size_t)(row0 + ar0) * K + ac0;
  const u16* Ar1 = A + (size_t)(row0 + ar1) * K + ac1;
  const u16* Br0 = Bt + (size_t)(col0 + ar0) * K + ac0;
  const u16* Br1 = Bt + (size_t)(col0 + ar1) * K + ac1;
  char* AsB = (char*)As;
  char* BsB = (char*)Bs;
  const int ldst = (t & ~63) * 16;  // wave-uniform LDS dest base

  for (int k0 = 0; k0 < K; k0 += 32) {
    __syncthreads();
    gload16(Ar0 + k0, AsB + ldst);
    gload16(Ar1 + k0, AsB + 4096 + ldst);
    gload16(Br0 + k0, BsB + ldst);
    gload16(Br1 + k0, BsB + 4096 + ldst);
    __syncthreads();
    s16x8 af[4], bfr[4];
#pragma unroll
    for (int m = 0; m < 4; ++m)
      af[m] = *(const s16x8*)&As[(wr * 64 + 16 * m + q) * 32 + g * 8];
#pragma unroll
    for (int n = 0; n < 4; ++n)
      bfr[n] = *(const s16x8*)&Bs[(wc * 64 + 16 * n + q) * 32 + g * 8];
#pragma unroll
    for (int m = 0; m < 4; ++m)
#pragma unroll
      for (int n = 0; n < 4; ++n) acc[m][n] = MFMA(af[m], bfr[n], acc[m][n]);
  }
#pragma unroll
  for (int n = 0; n < 4; ++n) {
    const int col = col0 + wc * 64 + 16 * n + q;
    const float bv = bias[col];
#pragma unroll
    for (int m = 0; m < 4; ++m) {
#pragma unroll
      for (int r = 0; r < 4; ++r) {
        const int row = row0 + wr * 64 + 16 * m + 4 * g + r;
        float v = acc[m][n][r] + bv;
        if (RELU) v = fmaxf(v, 0.f);
        if (OUTBF) Cb[(size_t)row * N + col] = f2bf(v);
        else Cf[(size_t)row * N + col] = v;
      }
    }
  }
}

// ---------------------------------------------------------------------------
// MFMA flash attention. qkv: [B*S][3072] bf16 (q|k|v slices). vt: [bh][64][S].
// Block: one (b,h) x 64 q-rows; 4 waves x 16 q-rows; KV tiles of 64.
// Swapped QK^T: S^T = K @ Q^T so lane owns q-row (l&15) for softmax.
// ---------------------------------------------------------------------------
__global__ __launch_bounds__(256) void attn_mfma(
    const u16* __restrict__ qkv, const u16* __restrict__ vt,
    u16* __restrict__ xb) {
  __shared__ __align__(128) u16 Qs[64 * 64];
  __shared__ __align__(128) u16 Ks[64 * 64];
  __shared__ __align__(128) u16 Vs[64 * 64];
  __shared__ __align__(128) u16 Ps[4 * 16 * 64];

  const int t = threadIdx.x;
  const int w = t >> 6;
  const int lane = t & 63;
  const int g = lane >> 4, q = lane & 15;
  const int bh = blockIdx.y;
  const int b = bh >> 4, h = bh & 15;
  const int q0 = blockIdx.x * 64;
  const int qcol = h * 64;
  const int kcol = DD + h * 64;
  const int ldst = (t & ~63) * 16;
  const u16* Pw = Ps + w * 1024;  // wave-private P region [16][64]

  // stage Q once (source pre-swizzled so linear LDS == swizzled layout)
  {
    const int r0 = t >> 3, p0 = (t & 7) ^ (r0 & 7);
    const int c1 = 256 + t, r1 = c1 >> 3, p1 = (c1 & 7) ^ (r1 & 7);
    gload16(qkv + ((size_t)(b * SS + q0 + r0) * 3072 + qcol + p0 * 8),
            (char*)Qs + ldst);
    gload16(qkv + ((size_t)(b * SS + q0 + r1) * 3072 + qcol + p1 * 8),
            (char*)Qs + 4096 + ldst);
  }

  float m_run = -1e30f, l_run = 0.f;
  f32x4v oacc[4];
#pragma unroll
  for (int n = 0; n < 4; ++n) oacc[n] = (f32x4v){0.f, 0.f, 0.f, 0.f};
  const float scale = 0.125f;

  for (int kt = 0; kt < SS / 64; ++kt) {
    const int s0 = kt * 64;
    __syncthreads();
    {
      const int r0 = t >> 3, p0 = (t & 7) ^ (r0 & 7);
      const int c1 = 256 + t, r1 = c1 >> 3, p1 = (c1 & 7) ^ (r1 & 7);
      gload16(qkv + ((size_t)(b * SS + s0 + r0) * 3072 + kcol + p0 * 8),
              (char*)Ks + ldst);
      gload16(qkv + ((size_t)(b * SS + s0 + r1) * 3072 + kcol + p1 * 8),
              (char*)Ks + 4096 + ldst);
      gload16(vt + ((size_t)(bh * 64 + r0) * SS + s0 + p0 * 8),
              (char*)Vs + ldst);
      gload16(vt + ((size_t)(bh * 64 + r1) * SS + s0 + p1 * 8),
              (char*)Vs + 4096 + ldst);
    }
    __syncthreads();

    // S^T[64k][16q] = K @ Q^T   (A = K rows, B = Q^T cols)
    s16x8 bq0 = ldfrag(Qs, w * 16 + q, g * 16);
    s16x8 bq1 = ldfrag(Qs, w * 16 + q, 64 + g * 16);
    f32x4v sacc[4];
#pragma unroll
    for (int m = 0; m < 4; ++m) {
      sacc[m] = (f32x4v){0.f, 0.f, 0.f, 0.f};
      s16x8 a0 = ldfrag(Ks, 16 * m + q, g * 16);
      s16x8 a1 = ldfrag(Ks, 16 * m + q, 64 + g * 16);
      sacc[m] = MFMA(a0, bq0, sacc[m]);
      sacc[m] = MFMA(a1, bq1, sacc[m]);
    }

    // online softmax for q-row = q (lane&15); lane's 16 k = 16m + 4g + r
    float sc[16];
    float tm = -1e30f;
#pragma unroll
    for (int m = 0; m < 4; ++m)
#pragma unroll
      for (int r = 0; r < 4; ++r) {
        float sv = sacc[m][r] * scale;
        sc[m * 4 + r] = sv;
        tm = fmaxf(tm, sv);
      }
    tm = fmaxf(tm, __shfl_xor(tm, 16));
    tm = fmaxf(tm, __shfl_xor(tm, 32));
    const float m_new = fmaxf(m_run, tm);
    const float rf = __expf(m_run - m_new);
    float psum = 0.f;
#pragma unroll
    for (int m = 0; m < 4; ++m) {
      u16x4 pw;
#pragma unroll
      for (int r = 0; r < 4; ++r) {
        float p = __expf(sc[m * 4 + r] - m_new);
        psum += p;
        pw[r] = f2bf(p);
      }
      const int cb = (32 * m + 8 * g) ^ ((q & 7) << 4);
      *(u16x4*)((char*)(Ps + w * 1024) + q * 128 + cb) = pw;
    }
    psum += __shfl_xor(psum, 16);
    psum += __shfl_xor(psum, 32);
    l_run = l_run * rf + psum;
    m_run = m_new;

    // broadcast rescale to O's C-layout rows (q_o = 4g + r lives at lane q_o)
    float rfo[4];
#pragma unroll
    for (int r = 0; r < 4; ++r) rfo[r] = __shfl(rf, 4 * g + r);
#pragma unroll
    for (int n = 0; n < 4; ++n) {
      oacc[n][0] *= rfo[0]; oacc[n][1] *= rfo[1];
      oacc[n][2] *= rfo[2]; oacc[n][3] *= rfo[3];
    }

    // O[16q][64d] += P @ V  (A = P rows from LDS, B = Vt cols)
#pragma unroll
    for (int s = 0; s < 2; ++s) {
      s16x8 ap = ldfrag(Pw, q, s * 64 + g * 16);
#pragma unroll
      for (int n = 0; n < 4; ++n) {
        s16x8 bv = ldfrag(Vs, 16 * n + q, s * 64 + g * 16);
        oacc[n] = MFMA(ap, bv, oacc[n]);
      }
    }
  }

  const float invl = 1.f / l_run;
  float invo[4];
#pragma unroll
  for (int r = 0; r < 4; ++r) invo[r] = __shfl(invl, 4 * g + r);
#pragma unroll
  for (int n = 0; n < 4; ++n)
#pragma unroll
    for (int r = 0; r < 4; ++r) {
      const size_t row = (size_t)(b * SS + q0 + w * 16 + 4 * g + r);
      xb[row * DD + h * 64 + 16 * n + q] = f2bf(oacc[n][r] * invo[r]);
    }
}

// ---------------------------------------------------------------------------
// helpers: f32->bf16 convert, weight transpose+convert, v-slice transpose,
// bias concat, residual+LN
// ---------------------------------------------------------------------------
__global__ __launch_bounds__(256) void cvt_bf16(const float* __restrict__ x,
                                                u16* __restrict__ y, int n4) {
  int i = blockIdx.x * 256 + threadIdx.x;
  if (i < n4) {
    float4 v = ((const float4*)x)[i];
    u16x4 o;
    o[0] = f2bf(v.x); o[1] = f2bf(v.y); o[2] = f2bf(v.z); o[3] = f2bf(v.w);
    ((u16x4*)y)[i] = o;
  }
}

// W[K][N] f32 -> Wt[N][K] bf16, 32x32 tiles
__global__ __launch_bounds__(256) void transpose_w(const float* __restrict__ W,
                                                   u16* __restrict__ Wt,
                                                   int K, int N) {
  __shared__ float T[32][33];
  const int n0 = blockIdx.x * 32, k0 = blockIdx.y * 32;
  const int t = threadIdx.x;
  const int r = t >> 3, c = (t & 7) * 4;
  float4 v = *(const float4*)&W[(size_t)(k0 + r) * N + n0 + c];
  T[r][c] = v.x; T[r][c + 1] = v.y; T[r][c + 2] = v.z; T[r][c + 3] = v.w;
  __syncthreads();
  const int a = t >> 3, b0 = (t & 7) * 4;
  u16x4 o;
#pragma unroll
  for (int j = 0; j < 4; ++j) o[j] = f2bf(T[b0 + j][a]);
  *(u16x4*)&Wt[(size_t)(n0 + a) * K + k0 + b0] = o;
}

// v slice of qkv -> vt[bh][d][s]
__global__ __launch_bounds__(256) void vtrans(const u16* __restrict__ qkv,
                                              u16* __restrict__ vt) {
  __shared__ u16 T[64 * 72];
  const int t = threadIdx.x;
  const int bh = blockIdx.y, b = bh >> 4, h = bh & 15;
  const int s0 = blockIdx.x * 64;
  const int vcol = 2048 + h * 64;
#pragma unroll
  for (int i = 0; i < 2; ++i) {
    int c = i * 256 + t;
    int sr = c >> 3, dc = (c & 7) * 8;
    *(u16x8*)&T[sr * 72 + dc] =
        *(const u16x8*)&qkv[(size_t)(b * SS + s0 + sr) * 3072 + vcol + dc];
  }
  __syncthreads();
#pragma unroll
  for (int i = 0; i < 2; ++i) {
    int c = i * 256 + t;
    int d = c >> 3, scnk = (c & 7) * 8;
    u16x8 o;
#pragma unroll
    for (int j = 0; j < 8; ++j) o[j] = T[(scnk + j) * 72 + d];
    *(u16x8*)&vt[(size_t)(bh * 64 + d) * SS + s0 + scnk] = o;
  }
}

__global__ __launch_bounds__(256) void concat3(const float* __restrict__ a,
                                               const float* __restrict__ b,
                                               const float* __restrict__ c,
                                               float* __restrict__ o) {
  int i = blockIdx.x * 256 + threadIdx.x;
  if (i < 3072)
    o[i] = i < 1024 ? a[i] : (i < 2048 ? b[i - 1024] : c[i - 2048]);
}

template <int WB>
__global__ __launch_bounds__(256) void ln_res(
    const float* __restrict__ X, const float* __restrict__ R,
    const float* __restrict__ g, const float* __restrict__ b,
    float* __restrict__ Y, u16* __restrict__ Yb) {
  const int row = blockIdx.x;
  const int t = threadIdx.x;
  const size_t off = (size_t)row * DD + t * 4;

  float4 x4 = *(const float4*)&X[off];
  float4 r4 = *(const float4*)&R[off];
  float v0 = x4.x + r4.x, v1 = x4.y + r4.y, v2 = x4.z + r4.z, v3 = x4.w + r4.w;

  float s1 = v0 + v1 + v2 + v3;
  float s2 = v0 * v0 + v1 * v1 + v2 * v2 + v3 * v3;
#pragma unroll
  for (int o = 1; o < 64; o <<= 1) {
    s1 += __shfl_xor(s1, o);
    s2 += __shfl_xor(s2, o);
  }
  __shared__ float red1[4], red2[4];
  if ((t & 63) == 0) {
    red1[t >> 6] = s1;
    red2[t >> 6] = s2;
  }
  __syncthreads();
  s1 = red1[0] + red1[1] + red1[2] + red1[3];
  s2 = red2[0] + red2[1] + red2[2] + red2[3];

  const float mu = s1 * (1.f / DD);
  const float var = s2 * (1.f / DD) - mu * mu;
  const float rs = rsqrtf(var + 1e-5f);

  float4 g4 = *(const float4*)&g[t * 4];
  float4 b4 = *(const float4*)&b[t * 4];
  float4 y;
  y.x = (v0 - mu) * rs * g4.x + b4.x;
  y.y = (v1 - mu) * rs * g4.y + b4.y;
  y.z = (v2 - mu) * rs * g4.z + b4.z;
  y.w = (v3 - mu) * rs * g4.w + b4.w;
  *(float4*)&Y[off] = y;
  if (WB) {
    u16x4 o;
    o[0] = f2bf(y.x); o[1] = f2bf(y.y); o[2] = f2bf(y.z); o[3] = f2bf(y.w);
    *(u16x4*)&Yb[off] = o;
  }
}

// ---------------------------------------------------------------------------
extern "C" void kernel_launch(void* const* d_in, const int* in_sizes, int n_in,
                              void* d_out, int out_size, void* d_ws,
                              size_t ws_size, hipStream_t stream) {
  const float* src = (const float*)d_in[0];
  const float* Wq  = (const float*)d_in[1];
  const float* bq  = (const float*)d_in[2];
  const float* Wk  = (const float*)d_in[3];
  const float* bk  = (const float*)d_in[4];
  const float* Wv  = (const float*)d_in[5];
  const float* bv  = (const float*)d_in[6];
  const float* Wo  = (const float*)d_in[7];
  const float* bo  = (const float*)d_in[8];
  const float* g1  = (const float*)d_in[9];
  const float* b1  = (const float*)d_in[10];
  const float* W1  = (const float*)d_in[11];
  const float* bf1 = (const float*)d_in[12];
  const float* W2  = (const float*)d_in[13];
  const float* bf2 = (const float*)d_in[14];
  const float* g2  = (const float*)d_in[15];
  const float* b2  = (const float*)d_in[16];

  char* W = (char*)d_ws;
  // byte offsets (lifetime-overlapped, total ~193 MB)
  u16*   wqkvT = (u16*)  (W + 0);          //  6,291,456
  u16*   woT   = (u16*)  (W + 6291456);    //  2,097,152
  u16*   w1T   = (u16*)  (W + 8388608);    //  8,388,608
  u16*   w2T   = (u16*)  (W + 16777216);   //  8,388,608
  float* bqkv  = (float*)(W + 25165824);   //     12,288
  u16*   srcb  = (u16*)  (W + 25178112);   // 16,777,216
  u16*   qkv   = (u16*)  (W + 41955328);   // 50,331,648
  u16*   vt    = (u16*)  (W + 92286976);   // 16,777,216
  u16*   xb    = (u16*)  (W + 109064192);  // 16,777,216
  float* pb    = (float*)(W + 125841408);  // 33,554,432
  float* s1f   = (float*)(W + 159395840);  // 33,554,432 -> end 192,950,272
  u16*   s1bb  = (u16*)  (W + 109064192);  // alias xb (dead after Wo GEMM)
  u16*   f1b   = (u16*)  (W + 41955328);   // alias qkv+vt (dead after attn)
  float* f2b   = (float*)(W + 125841408);  // alias pb (dead after LN1)

  dim3 blk(256);

  // prep: bf16 conversions / transposes
  cvt_bf16<<<8192, blk, 0, stream>>>(src, srcb, MR * DD / 4);
  transpose_w<<<dim3(32, 32), blk, 0, stream>>>(Wq, wqkvT, DD, DD);
  transpose_w<<<dim3(32, 32), blk, 0, stream>>>(Wk, wqkvT + (size_t)1024 * 1024, DD, DD);
  transpose_w<<<dim3(32, 32), blk, 0, stream>>>(Wv, wqkvT + (size_t)2048 * 1024, DD, DD);
  transpose_w<<<dim3(32, 32), blk, 0, stream>>>(Wo, woT, DD, DD);
  transpose_w<<<dim3(128, 32), blk, 0, stream>>>(W1, w1T, DD, PFF);
  transpose_w<<<dim3(32, 128), blk, 0, stream>>>(W2, w2T, PFF, DD);
  concat3<<<12, blk, 0, stream>>>(bq, bk, bv, bqkv);

  // fused QKV projection -> [8192][3072] bf16
  gemm_bf16<0, 1><<<dim3(24, 64), blk, 0, stream>>>(srcb, wqkvT, bqkv, nullptr,
                                                    qkv, MR, 3072, DD);
  // V transpose to [bh][d][s]
  vtrans<<<dim3(32, 64), blk, 0, stream>>>(qkv, vt);
  // attention -> xb bf16 [8192][1024]
  attn_mfma<<<dim3(32, 64), blk, 0, stream>>>(qkv, vt, xb);
  // output projection (fp32 out)
  gemm_bf16<0, 0><<<dim3(8, 64), blk, 0, stream>>>(xb, woT, bo, pb, nullptr,
                                                   MR, DD, DD);
  // residual + LN1 (fp32 + bf16 copies)
  ln_res<1><<<MR, blk, 0, stream>>>(src, pb, g1, b1, s1f, s1bb);
  // FFN
  gemm_bf16<1, 1><<<dim3(32, 64), blk, 0, stream>>>(s1bb, w1T, bf1, nullptr,
                                                    f1b, MR, PFF, DD);
  gemm_bf16<0, 0><<<dim3(8, 64), blk, 0, stream>>>(f1b, w2T, bf2, f2b, nullptr,
                                                   MR, DD, PFF);
  // residual + LN2 -> output
  ln_res<0><<<MR, blk, 0, stream>>>(s1f, f2b, g2, b2, (float*)d_out, nullptr);
}